// Round 6
// baseline (3943.898 us; speedup 1.0000x reference)
//
#include <hip/hip_runtime.h>
#include <math.h>

// ============================================================================
// StackedLSTM persistent-kernel R10 = R9 (tagged self-flagging channels) with
// LEGAL inline-asm operand types.
// R7/R8/R9 post-mortem: all three used HIP uint4/uint2 (classes, not native
// vectors) as asm operands -> invalid asm operand type, identical harness
// aborts. Fix: ext_vector_type natives (uint32x4/uint32x2) for every asm
// operand; zero_ws_k gets a dummy arg (macro edge). Protocol unchanged:
//   - h published as u32 {f16 | tag=tau+1}; c as 2 words {f32, tag}. Word
//     store atomicity replaces ordering: NO vmcnt drain, NO RAW flag, NO
//     acquire fence. Consumers stage h via sc0/sc1 dwordx4 loads retrying
//     stale 16B granules: the data load IS the poll.
//   - t==0 h_prev granules fabricated in-register as {0, tag=want}: no
//     init-tag reads exist -> no startup WAR race.
//   - x/weights stay L2-cached (no buffer_inv ever).
//   - flags = end-of-tick "tick tau reads done" tokens for WAR on the triple
//     buffers (writer at tau needs own+upper fl >= tau-2; skipped until
//     tau >= layer+3 where targets are reachable; early writes only hit
//     never-read zero-init buffers).
//   - spin caps (~40ms) turn any residual protocol bug into failed-with-
//     counters instead of a hang. 4 barriers/tick.
// Numerics identical to R4/R6 (same MFMA split/order, cvt, gates): absmax 0.25.
//
// g_ws u32-word layout:
//   [0,      196608)  hws  u32[4][3][32][512]   {f16 h | tag<<16}
//   [196608, 491520)  cws  u32[3][3][32][512][2] {f32 c, tag}
//   [491520, 492544)  flags[4][64] (16B stride)
// ============================================================================

#define TT 512
#define HH 512
#define ROWP 1032                    // padded LDS row length in f16
#define W_OFF 0
#define A_OFF 82560                  // 40*ROWP*2
#define RED_OFF A_OFF                // aliases A region (used after dots done)
#define LDS_BYTES (A_OFF + 66048)    // 148608 B -> 1 block/CU

#define CWS_OFF   196608
#define FL_OFF    491520
#define WS_ZERO_WORDS 492544

#define SPIN_CAP (1u<<16)            // failsafe: ~40ms >> any legit wait

typedef _Float16 half8 __attribute__((ext_vector_type(8)));
typedef float f32x4 __attribute__((ext_vector_type(4)));
typedef unsigned uint32x4 __attribute__((ext_vector_type(4)));
typedef unsigned uint32x2 __attribute__((ext_vector_type(2)));

__device__ __align__(16) unsigned g_ws[WS_ZERO_WORDS];

__global__ void zero_ws_k(int dummy){
    (void)dummy;
    int i = blockIdx.x*blockDim.x + threadIdx.x;
    for (; i < WS_ZERO_WORDS; i += gridDim.x*blockDim.x)
        __hip_atomic_store(g_ws + i, 0u, __ATOMIC_RELAXED, __HIP_MEMORY_SCOPE_AGENT);
}

__device__ __forceinline__ float sigm(float v){ return 1.f/(1.f+__expf(-v)); }

// Coherence-point ops: bypass L1/L2 so remote publishes are visible with no
// invalidate. Loads issued without waitcnt; pair with wait_vm0().
__device__ __forceinline__ void ld4_sys(uint32x4& d, const unsigned* p){
    asm volatile("global_load_dwordx4 %0, %1, off sc0 sc1" : "=&v"(d) : "v"(p));
}
__device__ __forceinline__ void ld2_sys(uint32x2& d, const unsigned* p){
    asm volatile("global_load_dwordx2 %0, %1, off sc0 sc1" : "=&v"(d) : "v"(p));
}
__device__ __forceinline__ void st1_sys(unsigned* p, unsigned v){
    asm volatile("global_store_dword %0, %1, off sc0 sc1" :: "v"(p), "v"(v) : "memory");
}
__device__ __forceinline__ void st2_sys(unsigned* p, uint32x2 v){
    asm volatile("global_store_dwordx2 %0, %1, off sc0 sc1" :: "v"(p), "v"(v) : "memory");
}
__device__ __forceinline__ void wait_vm0(){
    asm volatile("s_waitcnt vmcnt(0)" ::: "memory");
    __builtin_amdgcn_sched_barrier(0);   // rule #18: pin consumers after wait
}

// Wave-cooperative WAR poll: lane i watches flags[L][i] until all >= need.
__device__ __forceinline__ void poll_layer(const unsigned* fl, int L, unsigned need){
    const int i = threadIdx.x & 63;
    const unsigned* p = fl + (L*64 + i)*4;
    for (unsigned spin = 0; spin < SPIN_CAP; ++spin){
        const unsigned v = __hip_atomic_load(p, __ATOMIC_RELAXED, __HIP_MEMORY_SCOPE_AGENT);
        if (__all((int)(v >= need))) break;
        __builtin_amdgcn_s_sleep(2);
    }
}

// MT=2: layer 0 (LSTM, 32 gate-rows). MT=3: CALSTM (40 rows, rows 40-47 junk).
template<int MT>
__device__ void run_loop(const float* __restrict__ x, const float* __restrict__ b_ih,
                         const float* __restrict__ b_hh, const float* __restrict__ ca_b,
                         float* __restrict__ out, char* lds, int layer, int ub)
{
    const int tid  = threadIdx.x;
    const int lane = tid & 63;
    const int wv   = tid >> 6;              // wave id 0..7 = K-eighth
    const int i16  = lane & 15, qq = lane >> 4;
    unsigned* hws = g_ws;                   // u32[l][buf][b][512]
    unsigned* cwsw = g_ws + CWS_OFF;        // u32 pairs [l][buf][b][512][2]
    unsigned* fl  = g_ws + FL_OFF;
    float* red = (float*)(lds + RED_OFF);

    // gate-thread invariants (tid<256): unit gu, batch gb, global unit gj
    const int gu = tid & 7, gb = tid >> 3, gj = ub*8 + gu;
    float bias[5] = {0,0,0,0,0};
    if (tid < 256){
        if (MT == 2){
#pragma unroll
            for (int g = 0; g < 4; ++g) bias[g] = b_ih[g*512+gj] + b_hh[g*512+gj];
        } else {
            const float* cbl = ca_b + (layer-1)*2560;
#pragma unroll
            for (int g = 0; g < 5; ++g) bias[g] = cbl[g*512+gj];
            bias[1] += 1.f; bias[2] += 1.f;   // fold the +1.0 of f_prev/f_low
        }
    }

    float creg = 0.f;   // register-carried c(t-1) for this (gu,gb)

    // h-staging role: MT2 splits x-half / h-half; MT3 everyone stages h.
    const bool hstage = (MT == 3) || ((tid & 127) >= 64);

    for (int tau = layer; tau < TT + layer; ++tau){
        const int t  = tau - layer;
        const int pb = tau % 3;           // publish buffer
        const int qb = (tau + 2) % 3;     // read buffer = (tau-1)%3
        const unsigned want = (unsigned)tau;

        unsigned* hprev_u = hws + (layer*3 + qb)*16384;
        unsigned* hlow_u  = (MT == 3) ? hws + ((layer-1)*3 + qb)*16384 : (unsigned*)0;

        // ---- issue tagged h loads (the staging load IS the wait) ----
        uint32x4 hv[16];
        const unsigned* ap[8];
        bool fab[8];
        if (hstage){
            const unsigned fw = want << 16;
            const uint32x4 fresh0 = {fw, fw, fw, fw};
#pragma unroll
            for (int it = 0; it < 8; ++it){
                const int cidx = tid + it*512;
                const int b = cidx >> 7, kc = (cidx & 127) << 3;
                const bool isprev = (MT == 2) || (kc >= 512);
                const unsigned* src = (MT == 2)
                    ? (hprev_u + b*512 + (kc - 512))
                    : ((kc < 512) ? (hlow_u + b*512 + kc)
                                  : (hprev_u + b*512 + (kc - 512)));
                ap[it] = src;
                fab[it] = (t == 0) && isprev;
                if (fab[it]){
                    hv[it*2] = fresh0; hv[it*2+1] = fresh0;
                } else {
                    ld4_sys(hv[it*2],   src);
                    ld4_sys(hv[it*2+1], src + 4);
                }
            }
        }
        // c_low early issue (checked at gate phase)
        uint32x2 cl = {0u, 0u};
        const unsigned* clp = (const unsigned*)0;
        if (MT == 3 && tid < 256){
            clp = cwsw + 2*(((layer-1)*3 + qb)*16384 + gb*512 + gj);
            ld2_sys(cl, clp);
        }
        // x prefetch (layer 0, x-half threads; normal cached loads — L2 warm)
        uint32x4 xpk[8];
        if (MT == 2 && (tid & 127) < 64){
#pragma unroll
            for (int it = 0; it < 8; ++it){
                const int cidx = tid + it*512;
                const int b = cidx >> 7, kc = (cidx & 127) << 3;   // kc < 512
                const float* xs = x + ((size_t)b*TT + t)*HH + kc;
                const float4 a = *(const float4*)xs;
                const float4 c = *(const float4*)(xs + 4);
                union { _Float16 h[8]; uint32x4 u; } pk;
                pk.h[0]=(_Float16)a.x; pk.h[1]=(_Float16)a.y;
                pk.h[2]=(_Float16)a.z; pk.h[3]=(_Float16)a.w;
                pk.h[4]=(_Float16)c.x; pk.h[5]=(_Float16)c.y;
                pk.h[6]=(_Float16)c.z; pk.h[7]=(_Float16)c.w;
                xpk[it] = pk.u;
            }
        }

        if (hstage || (MT == 3 && tid < 256)) wait_vm0();

        // ---- tag-retry: reissue only stale 16B granules until fresh ----
        if (hstage){
            for (unsigned spin = 0; spin < SPIN_CAP; ++spin){
                bool any = false;
#pragma unroll
                for (int it = 0; it < 8; ++it){
                    if (fab[it]) continue;
#pragma unroll
                    for (int h2 = 0; h2 < 2; ++h2){
                        uint32x4& v = hv[it*2 + h2];
                        const bool st = ((v[0]>>16)!=want) || ((v[1]>>16)!=want) ||
                                        ((v[2]>>16)!=want) || ((v[3]>>16)!=want);
                        if (st){ any = true; ld4_sys(v, ap[it] + h2*4); }
                    }
                }
                if (__all((int)(!any))) break;
                wait_vm0();
            }
        }

        // ---- stage A = [x_t | h_low ; h_prev] into LDS (packed f16) ----
        if (MT == 2 && (tid & 127) < 64){
#pragma unroll
            for (int it = 0; it < 8; ++it){
                const int cidx = tid + it*512;
                const int b = cidx >> 7, kc = (cidx & 127) << 3;
                *(uint32x4*)(lds + A_OFF + (size_t)(b*ROWP + kc)*2) = xpk[it];
            }
        }
        if (hstage){
#pragma unroll
            for (int it = 0; it < 8; ++it){
                const int cidx = tid + it*512;
                const int b = cidx >> 7, kc = (cidx & 127) << 3;
                const uint32x4 v0 = hv[it*2], v1 = hv[it*2+1];
                uint32x4 p;
                p[0] = (v0[0] & 0xffffu) | (v0[1] << 16);
                p[1] = (v0[2] & 0xffffu) | (v0[3] << 16);
                p[2] = (v1[0] & 0xffffu) | (v1[1] << 16);
                p[3] = (v1[2] & 0xffffu) | (v1[3] << 16);
                *(uint32x4*)(lds + A_OFF + (size_t)(b*ROWP + kc)*2) = p;
            }
        }

        // ---- WAR tokens: buffer written this tick (pb) was last read at tick
        // tau-2 (flags set at reader tick end). Skip until tau>=layer+3: the
        // early unguarded writes only overwrite never-read init zeros.
        if (tau >= layer + 3){
            if (wv == 2)                   poll_layer(fl, layer,   (unsigned)(tau-2));
            else if (wv == 3 && layer < 3) poll_layer(fl, layer+1, (unsigned)(tau-2));
        }
        __syncthreads();                                  // S2

        // ---- MFMA dots: this wave covers K-range [wv*128, wv*128+128) ----
        f32x4 acc[MT][2];
#pragma unroll
        for (int mt = 0; mt < MT; ++mt){ acc[mt][0] = (f32x4){0,0,0,0}; acc[mt][1] = (f32x4){0,0,0,0}; }
#pragma unroll
        for (int s = 0; s < 4; ++s){
            const int koff = wv*128 + s*32 + qq*8;
            half8 bfrag0 = *(const half8*)(lds + A_OFF + ((0*16 + i16)*ROWP + koff)*2);
            half8 bfrag1 = *(const half8*)(lds + A_OFF + ((1*16 + i16)*ROWP + koff)*2);
#pragma unroll
            for (int mt = 0; mt < MT; ++mt){
                half8 afrag = *(const half8*)(lds + W_OFF + ((mt*16 + i16)*ROWP + koff)*2);
                acc[mt][0] = __builtin_amdgcn_mfma_f32_16x16x32_f16(afrag, bfrag0, acc[mt][0], 0, 0, 0);
                acc[mt][1] = __builtin_amdgcn_mfma_f32_16x16x32_f16(afrag, bfrag1, acc[mt][1], 0, 0, 0);
            }
        }
        __syncthreads();            // S3: A reads done; RED aliases A

        // ---- K-partials, XOR-permuted: writes and reads <=2-way banks ----
#pragma unroll
        for (int mt = 0; mt < MT; ++mt)
#pragma unroll
            for (int nt = 0; nt < 2; ++nt)
#pragma unroll
                for (int r = 0; r < 4; ++r)
                    red[((((wv*MT + mt)*2 + nt)*4 + r)*4 + qq)*16 + ((i16 + 4*r)&15)] = acc[mt][nt][r];
        __syncthreads();                                  // S4

        // ---- fused reduce + gates + publish (tid<256) ----
        float hval = 0.f, cval = 0.f;
        if (tid < 256){
            const int NG = (MT == 2) ? 4 : 5;
            float mg[5];
#pragma unroll
            for (int g = 0; g < NG; ++g){
                const int m = g*8 + gu, mt2 = m >> 4, mr = m & 15, q2 = mr >> 2, r2 = mr & 3;
                const int nt2 = gb >> 4, i2 = gb & 15;
                const int base = (((mt2*2 + nt2)*4 + r2)*4 + q2)*16 + ((i2 + 4*r2)&15);
                float sm = 0.f;
#pragma unroll
                for (int kv = 0; kv < 8; ++kv) sm += red[base + kv*MT*512];
                mg[g] = sm + bias[g];
            }
            float clov = 0.f;
            if (MT == 3){
                for (unsigned spin = 0; cl[1] != want && spin < SPIN_CAP; ++spin){
                    ld2_sys(cl, clp);      // c tag-retry (usually pre-fresh)
                    wait_vm0();
                }
                clov = __uint_as_float(cl[0]);
            }
            if (MT == 2){
                cval = sigm(mg[0])*tanhf(mg[2]) + sigm(mg[1])*creg;
                hval = sigm(mg[3])*tanhf(cval);
            } else {
                cval = creg*sigm(mg[1]) + clov*sigm(mg[2]) + tanhf(mg[3])*sigm(mg[0]);
                hval = sigm(mg[4])*tanhf(cval);
            }
            creg = cval;

            // publish: tagged words, fire-and-forget (word atomicity = ordering)
            union { _Float16 f; unsigned short s; } cvt; cvt.f = (_Float16)hval;
            const unsigned hw = (unsigned)cvt.s | ((unsigned)(tau + 1) << 16);
            st1_sys(hws + ((layer*3 + pb)*16384 + gb*512 + gj), hw);
            if (layer < 3){
                uint32x2 cw = {__float_as_uint(cval), (unsigned)(tau + 1)};
                st2_sys(cwsw + 2*((layer*3 + pb)*16384 + gb*512 + gj), cw);
            }
        }
        __syncthreads();                                  // S5: all reads done
        if (tid == 0)
            __hip_atomic_store(fl + (layer*64 + ub)*4, (unsigned)tau,
                               __ATOMIC_RELAXED, __HIP_MEMORY_SCOPE_AGENT);

        // ---- outputs (not consumed on-device; off critical path) ----
        if (layer == 3 && tid < 256){
            const size_t pos = ((size_t)gb*TT + t)*HH + gj;
            out[pos]           = hval;
            out[8388608 + pos] = cval;
            if (t == TT-1){
                out[16777216 + (size_t)gb*HH + gj] = hval;
                out[16793600 + (size_t)gb*HH + gj] = cval;
            }
        }
    }
    // no sentinel needed: neighbors' max WAR need (TT+l-3) <= our final flag.
}

__global__ __launch_bounds__(512) void persist_k(
    const float* __restrict__ x, const float* __restrict__ w_ih,
    const float* __restrict__ w_hh, const float* __restrict__ b_ih,
    const float* __restrict__ b_hh, const float* __restrict__ ca_w,
    const float* __restrict__ ca_b, float* __restrict__ out)
{
    extern __shared__ char lds[];
    const int bx = blockIdx.x;
    const int layer = bx >> 6, ub = bx & 63;
    const int tid = threadIdx.x;
    const int rows = (layer == 0) ? 32 : 40;

    // one-time: weights fp32 -> f16 into LDS. local row r=g*8+u maps to
    // global gate-matrix row g*512 + ub*8 + u.
    for (int idx = tid; idx < rows*256; idx += 512){
        const int r = idx >> 8, k4 = (idx & 255) * 4;
        const int g = r >> 3, u = r & 7;
        const int grow = g*512 + ub*8 + u;
        const float* src;
        if (layer == 0) src = (k4 < 512) ? (w_ih + (size_t)grow*512 + k4)
                                         : (w_hh + (size_t)grow*512 + (k4 - 512));
        else            src = ca_w + (size_t)(layer-1)*2560*1024 + (size_t)grow*1024 + k4;
        const float4 v = *(const float4*)src;
        union { _Float16 h[4]; uint32x2 u2; } pk;
        pk.h[0]=(_Float16)v.x; pk.h[1]=(_Float16)v.y;
        pk.h[2]=(_Float16)v.z; pk.h[3]=(_Float16)v.w;
        *(uint32x2*)(lds + W_OFF + ((size_t)(r*ROWP + k4))*2) = pk.u2;
    }
    // first tick's S2 __syncthreads orders weight-load before MFMA use.
    if (layer == 0) run_loop<2>(x, b_ih, b_hh, ca_b, out, lds, layer, ub);
    else            run_loop<3>(x, b_ih, b_hh, ca_b, out, lds, layer, ub);
}

extern "C" void kernel_launch(void* const* d_in, const int* in_sizes, int n_in,
                              void* d_out, int out_size, void* d_ws, size_t ws_size,
                              hipStream_t stream)
{
    const float* x    = (const float*)d_in[0];
    const float* w_ih = (const float*)d_in[1];
    const float* w_hh = (const float*)d_in[2];
    const float* b_ih = (const float*)d_in[3];
    const float* b_hh = (const float*)d_in[4];
    const float* ca_w = (const float*)d_in[5];
    const float* ca_b = (const float*)d_in[6];
    float* out = (float*)d_out;
    (void)d_ws; (void)ws_size;   // channels live in static g_ws (1.97 MB)

    (void)hipFuncSetAttribute((const void*)persist_k,
                              hipFuncAttributeMaxDynamicSharedMemorySize, LDS_BYTES);
    hipLaunchKernelGGL(zero_ws_k, dim3(64), dim3(256), 0, stream, 0);
    hipLaunchKernelGGL(persist_k, dim3(256), dim3(512), LDS_BYTES, stream,
                       x, w_ih, w_hh, b_ih, b_hh, ca_w, ca_b, out);
}